// Round 10
// baseline (34.095 us; speedup 1.0000x reference)
//
#include <hip/hip_runtime.h>

#define BB 4
#define SS 512
#define IND 32
#define HH 64
#define NCC 3

#define IPB 8                      // i's per k2 block
#define NPB (BB * 128)             // 512 pair blocks: (b, ic, jc)
#define NNB 512                    // node blocks (4 nodes each)

// workspace layout (floats)
#define OFF_U    0                        // [2048][64]
#define OFF_V    (OFF_U + BB*SS*HH)       // float4-interleaved: elem (j>>2)*64+h, comp j&3
#define OFF_P    (OFF_V + BB*SS*HH)       // [2048][32]
#define OFF_QT   (OFF_P + BB*SS*32)       // float4-interleaved: elem (k>>2)*2048+n, comp k&3
#define OFF_SN   (OFF_QT + 32*BB*SS)      // [512][64]
#define OFF_SA   (OFF_SN + NNB*HH)        // [512][64]
#define OFF_SH   (OFF_SA + NPB*HH)        // [512][64]
#define OFF_SKP  (OFF_SH + NPB*HH)        // [512*16] stride 64B

__global__ __launch_bounds__(256) void k_nodes(
    const float* __restrict__ x,  const float* __restrict__ W1, const float* __restrict__ b1,
    const float* __restrict__ W2, const float* __restrict__ b2,
    const float* __restrict__ We1,const float* __restrict__ be1,
    const float* __restrict__ Wd1,const float* __restrict__ bd1,
    float* __restrict__ ws)
{
    float* U = ws + OFF_U;  float* V4 = ws + OFF_V;
    float* P = ws + OFF_P;  float* Qt4 = ws + OFF_QT;
    float* SN = ws + OFF_SN;
    __shared__ float sn_lds[4][64];
    const int tid = threadIdx.x, wave = tid >> 6, lane = tid & 63;
    const int node = blockIdx.x * 4 + wave;   // 2048 nodes

    float xv = (lane < IND) ? x[node * IND + lane] : 0.0f;
    float h1 = b1[lane];
    #pragma unroll
    for (int k = 0; k < IND; k++)
        h1 = fmaf(__shfl(xv, k, 64), W1[k * HH + lane], h1);
    h1 = fmaxf(h1, 0.0f);

    float nd = b2[lane];
    #pragma unroll 16
    for (int k = 0; k < HH; k++)
        nd = fmaf(__shfl(h1, k, 64), W2[k * HH + lane], nd);

    float uv = be1[lane];
    float vv = 0.0f;
    float pq = (lane < 32) ? bd1[lane] : 0.0f;
    const float* WdCol = (lane < 32) ? (Wd1 + lane) : (Wd1 + HH * 32 + (lane - 32));
    #pragma unroll 16
    for (int k = 0; k < HH; k++) {
        float s = __shfl(nd, k, 64);
        uv = fmaf(s, We1[k * HH + lane], uv);
        vv = fmaf(s, We1[(HH + k) * HH + lane], vv);
        pq = fmaf(s, WdCol[k * 32], pq);
    }
    U[node * HH + lane] = uv;
    // V interleaved-4: elem (node>>2)*64 + h, comp node&3 (= wave)
    V4[(blockIdx.x * 64 + lane) * 4 + wave] = vv;
    if (lane < 32) {
        P[node * 32 + lane] = pq;
    } else {
        int k = lane - 32;
        Qt4[((k >> 2) * (BB * SS) + node) * 4 + (k & 3)] = pq;
    }

    sn_lds[wave][lane] = nd;
    __syncthreads();
    if (tid < 64)
        SN[blockIdx.x * 64 + tid] = (sn_lds[0][tid] + sn_lds[1][tid]) + (sn_lds[2][tid] + sn_lds[3][tid]);
}

__global__ __launch_bounds__(256, 2) void k_pairs(
    const float* __restrict__ wd2, const float* __restrict__ bd2,
    float* __restrict__ ws)
{
    const float*  U   = ws + OFF_U;
    const float4* V4  = (const float4*)(ws + OFF_V);
    const float*  P   = ws + OFF_P;
    const float4* Qt4 = (const float4*)(ws + OFF_QT);
    float* SA = ws + OFF_SA;  float* SHo = ws + OFF_SH;  float* SKp = ws + OFF_SKP;

    __shared__ float4 gsA[4][64], gsB[4][64];  // 8 gates per (wave, j)
    __shared__ float redA[4][64], redH[4][64], redK[4];

    const int tid = threadIdx.x, wave = tid >> 6, lane = tid & 63;
    const int b  = blockIdx.x >> 7;            // 128 blocks per batch
    const int ic = (blockIdx.x >> 1) & 63;
    const int jc = blockIdx.x & 1;
    const int i0 = ic * IPB;
    const int jbase = b * SS + jc * 256 + wave * 64;   // this wave's 64 j's (global)

    // ---- issue ALL fat loads up front (gate VALU hides V latency) ----
    const float4* Qp = Qt4 + jbase + lane;
    const float4* Vp = V4 + (jbase >> 2) * 64 + lane;
    float4 q[8], v[16];
    #pragma unroll
    for (int kg = 0; kg < 8; kg++) q[kg] = Qp[kg * (BB * SS)];
    #pragma unroll
    for (int jq = 0; jq < 16; jq++) v[jq] = Vp[jq * 64];

    float u[IPB];
    #pragma unroll
    for (int i = 0; i < IPB; i++) u[i] = U[(b * SS + i0 + i) * HH + lane];

    const float* Pb = P + (b * SS + i0) * 32;  // block-uniform -> s_load path
    const float bd2v = bd2[0];

    // ---- gate: lane <-> j; P/wd2 via scalar loads (no readlane) ----
    float a[IPB];
    #pragma unroll
    for (int i = 0; i < IPB; i++) a[i] = bd2v;
    #pragma unroll
    for (int kg = 0; kg < 8; kg++) {
        #pragma unroll
        for (int t = 0; t < 4; t++) {
            const int k = kg * 4 + t;
            float qv = (t == 0) ? q[kg].x : (t == 1) ? q[kg].y : (t == 2) ? q[kg].z : q[kg].w;
            float w  = wd2[k];                 // uniform -> SGPR
            #pragma unroll
            for (int i = 0; i < IPB; i++)
                a[i] = fmaf(w, fmaxf(Pb[i * 32 + k] + qv, 0.0f), a[i]);
        }
    }
    float g[IPB], sk = 0.0f;
    #pragma unroll
    for (int i = 0; i < IPB; i++) {
        g[i] = 1.0f / (1.0f + __expf(-a[i]));
        sk += g[i];
    }
    gsA[wave][lane] = make_float4(g[0], g[1], g[2], g[3]);
    gsB[wave][lane] = make_float4(g[4], g[5], g[6], g[7]);
    __builtin_amdgcn_wave_barrier();           // same wave produces & consumes its gs rows

    // ---- accumulate: lane <-> h comp; gates via 2 uniform b128 reads per j ----
    float sa[IPB] = {0,0,0,0,0,0,0,0};
    float sh = 0.0f;
    #pragma unroll
    for (int jq = 0; jq < 16; jq++) {
        #pragma unroll
        for (int t = 0; t < 4; t++) {
            float vv = (t == 0) ? v[jq].x : (t == 1) ? v[jq].y : (t == 2) ? v[jq].z : v[jq].w;
            float4 ga = gsA[wave][jq * 4 + t];
            float4 gb = gsB[wave][jq * 4 + t];
            float h0 = fmaxf(u[0] + vv, 0.0f);
            float h1 = fmaxf(u[1] + vv, 0.0f);
            float h2 = fmaxf(u[2] + vv, 0.0f);
            float h3 = fmaxf(u[3] + vv, 0.0f);
            float h4 = fmaxf(u[4] + vv, 0.0f);
            float h5 = fmaxf(u[5] + vv, 0.0f);
            float h6 = fmaxf(u[6] + vv, 0.0f);
            float h7 = fmaxf(u[7] + vv, 0.0f);
            sh += ((h0 + h1) + (h2 + h3)) + ((h4 + h5) + (h6 + h7));
            sa[0] = fmaf(ga.x, h0, sa[0]);
            sa[1] = fmaf(ga.y, h1, sa[1]);
            sa[2] = fmaf(ga.z, h2, sa[2]);
            sa[3] = fmaf(ga.w, h3, sa[3]);
            sa[4] = fmaf(gb.x, h4, sa[4]);
            sa[5] = fmaf(gb.y, h5, sa[5]);
            sa[6] = fmaf(gb.z, h6, sa[6]);
            sa[7] = fmaf(gb.w, h7, sa[7]);
        }
    }
    float saT = ((sa[0] + sa[1]) + (sa[2] + sa[3])) + ((sa[4] + sa[5]) + (sa[6] + sa[7]));

    redA[wave][lane] = saT;
    redH[wave][lane] = sh;
    #pragma unroll
    for (int off = 32; off; off >>= 1) sk += __shfl_xor(sk, off, 64);
    if (lane == 0) redK[wave] = sk;
    __syncthreads();

    // ---- plain coalesced partial stores; kernel boundary publishes them ----
    if (tid < 64) {
        SA[blockIdx.x * 64 + tid]  = (redA[0][tid] + redA[1][tid]) + (redA[2][tid] + redA[3][tid]);
        SHo[blockIdx.x * 64 + tid] = (redH[0][tid] + redH[1][tid]) + (redH[2][tid] + redH[3][tid]);
        if (tid == 0)
            SKp[blockIdx.x * 16] = (redK[0] + redK[1]) + (redK[2] + redK[3]);
    }
}

__global__ __launch_bounds__(256) void k_final(
    const float* __restrict__ We2, const float* __restrict__ be2,
    const float* __restrict__ Wc1, const float* __restrict__ bc1,
    const float* __restrict__ Wc2, const float* __restrict__ bc2,
    const float* __restrict__ ws, float* __restrict__ out)
{
    const float4* SN4 = (const float4*)(ws + OFF_SN);   // [512 rows][16]
    const float4* SA4 = (const float4*)(ws + OFF_SA);   // [512 rows][16]
    const float4* SH4 = (const float4*)(ws + OFF_SH);
    const float*  SKp = ws + OFF_SKP;
    __shared__ float4 r4[3][16][16];                    // [arr][grp][l16]
    __shared__ float redS[128], saL[64], shL[64];
    __shared__ float featL[128], c1L[32];
    const int tid = threadIdx.x, wave = tid >> 6, lane = tid & 63;
    const int grp = tid >> 4, l16 = tid & 15;
    const int b = blockIdx.x;                  // 4 blocks, one per batch

    // ---- float4 partial sums over 128 rows each ----
    float4 sn4 = make_float4(0.f, 0.f, 0.f, 0.f);
    float4 sa4 = sn4, sh4 = sn4;
    #pragma unroll
    for (int r = 0; r < 8; r++) {
        float4 t0 = SN4[(b * 128 + r * 16 + grp) * 16 + l16];
        float4 t1 = SA4[(b * 128 + r * 16 + grp) * 16 + l16];
        float4 t2 = SH4[(b * 128 + r * 16 + grp) * 16 + l16];
        sn4.x += t0.x; sn4.y += t0.y; sn4.z += t0.z; sn4.w += t0.w;
        sa4.x += t1.x; sa4.y += t1.y; sa4.z += t1.z; sa4.w += t1.w;
        sh4.x += t2.x; sh4.y += t2.y; sh4.z += t2.z; sh4.w += t2.w;
    }
    r4[0][grp][l16] = sn4;  r4[1][grp][l16] = sa4;  r4[2][grp][l16] = sh4;
    if (tid < 128) redS[tid] = SKp[(b * 128 + tid) * 16];
    __syncthreads();

    if (wave == 0) {                           // lane = tid, one h each
        const int li = lane >> 2, comp = lane & 3;
        float snT = 0.f, saF = 0.f, shF = 0.f;
        #pragma unroll
        for (int g = 0; g < 16; g++) {
            snT += ((const float*)&r4[0][g][li])[comp];
            saF += ((const float*)&r4[1][g][li])[comp];
            shF += ((const float*)&r4[2][g][li])[comp];
        }
        float skp = redS[lane] + redS[64 + lane];
        #pragma unroll
        for (int off = 32; off; off >>= 1) skp += __shfl_xor(skp, off, 64);
        saL[lane] = saF;  shL[lane] = shF;

        float as = skp * be2[lane];
        float ts = (262144.0f - skp) * be2[lane];     // S*S - SK
        #pragma unroll 8
        for (int k = 0; k < HH; k++) {
            float w = We2[k * HH + lane];
            float sak = saL[k];
            as = fmaf(sak, w, as);
            ts = fmaf(shL[k] - sak, w, ts);
        }
        featL[lane]      = (snT + as) * (1.0f / 512.0f);
        featL[64 + lane] = ts * (1.0f / 512.0f);
    }
    __syncthreads();

    if (tid < 32) {
        float c1 = bc1[tid];
        #pragma unroll 8
        for (int k = 0; k < 128; k++)
            c1 = fmaf(featL[k], Wc1[k * 32 + tid], c1);
        c1L[tid] = fmaxf(c1, 0.0f);
    }
    __syncthreads();
    if (tid < NCC) {
        float o = bc2[tid];
        #pragma unroll
        for (int k = 0; k < 32; k++)
            o = fmaf(c1L[k], Wc2[k * NCC + tid], o);
        out[b * NCC + tid] = o;
    }
}

extern "C" void kernel_launch(void* const* d_in, const int* in_sizes, int n_in,
                              void* d_out, int out_size, void* d_ws, size_t ws_size,
                              hipStream_t stream) {
    const float* x   = (const float*)d_in[0];
    const float* W1  = (const float*)d_in[1];
    const float* b1  = (const float*)d_in[2];
    const float* W2  = (const float*)d_in[3];
    const float* b2  = (const float*)d_in[4];
    const float* We1 = (const float*)d_in[5];
    const float* be1 = (const float*)d_in[6];
    const float* We2 = (const float*)d_in[7];
    const float* be2 = (const float*)d_in[8];
    const float* Wd1 = (const float*)d_in[9];
    const float* bd1 = (const float*)d_in[10];
    const float* wd2 = (const float*)d_in[11];
    const float* bd2 = (const float*)d_in[12];
    const float* Wc1 = (const float*)d_in[13];
    const float* bc1 = (const float*)d_in[14];
    const float* Wc2 = (const float*)d_in[15];
    const float* bc2 = (const float*)d_in[16];
    float* ws  = (float*)d_ws;
    float* out = (float*)d_out;

    k_nodes<<<dim3(NNB), dim3(256), 0, stream>>>(x, W1, b1, W2, b2, We1, be1, Wd1, bd1, ws);
    k_pairs<<<dim3(NPB), dim3(256), 0, stream>>>(wd2, bd2, ws);
    k_final<<<dim3(BB), dim3(256), 0, stream>>>(We2, be2, Wc1, bc1, Wc2, bc2, ws, out);
}

// Round 12
// 33.459 us; speedup vs baseline: 1.0190x; 1.0190x over previous
//
#include <hip/hip_runtime.h>

#define BB 4
#define SS 512
#define IND 32
#define HH 64
#define NCC 3

#define IPB 4                      // i's per k2 block
#define NPB (BB * 256)             // 1024 pair blocks: (b, ic, jc)
#define NNB 512                    // node blocks (4 nodes each)

// workspace layout (floats)
#define OFF_U    0                        // [2048][64]
#define OFF_V    (OFF_U + BB*SS*HH)       // float4-interleaved: elem (j>>2)*64+h, comp j&3
#define OFF_P    (OFF_V + BB*SS*HH)       // [2048][32]
#define OFF_QT   (OFF_P + BB*SS*32)       // float4-interleaved: elem (k>>2)*2048+n, comp k&3
#define OFF_SN   (OFF_QT + 32*BB*SS)      // [512][64] by logical node-block
#define OFF_SA   (OFF_SN + NNB*HH)        // [1024][64] by logical pair index
#define OFF_SH   (OFF_SA + NPB*HH)        // [1024][64]
#define OFF_SKP  (OFF_SH + NPB*HH)        // [1024*16] stride 64B

__device__ __forceinline__ float rl(float v, int l) {
    return __uint_as_float(__builtin_amdgcn_readlane(__float_as_uint(v), l));
}

__global__ __launch_bounds__(256) void k_nodes(
    const float* __restrict__ x,  const float* __restrict__ W1, const float* __restrict__ b1,
    const float* __restrict__ W2, const float* __restrict__ b2,
    const float* __restrict__ We1,const float* __restrict__ be1,
    const float* __restrict__ Wd1,const float* __restrict__ bd1,
    float* __restrict__ ws)
{
    float* U = ws + OFF_U;  float* V4 = ws + OFF_V;
    float* P = ws + OFF_P;  float* Qt4 = ws + OFF_QT;
    float* SN = ws + OFF_SN;
    __shared__ float sn_lds[4][64];
    const int tid = threadIdx.x, wave = tid >> 6, lane = tid & 63;
    // XCD co-location: dispatch d -> XCD d&7 (round-robin); logical block L so that
    // XCD x writes the contiguous node chunk [256x, 256x+256).
    const int L = ((blockIdx.x & 7) << 6) | (blockIdx.x >> 3);
    const int node = L * 4 + wave;            // 2048 nodes

    float xv = (lane < IND) ? x[node * IND + lane] : 0.0f;
    float h1 = b1[lane];
    #pragma unroll
    for (int k = 0; k < IND; k++)
        h1 = fmaf(__shfl(xv, k, 64), W1[k * HH + lane], h1);
    h1 = fmaxf(h1, 0.0f);

    float nd = b2[lane];
    #pragma unroll 16
    for (int k = 0; k < HH; k++)
        nd = fmaf(__shfl(h1, k, 64), W2[k * HH + lane], nd);

    float uv = be1[lane];
    float vv = 0.0f;
    float pq = (lane < 32) ? bd1[lane] : 0.0f;
    const float* WdCol = (lane < 32) ? (Wd1 + lane) : (Wd1 + HH * 32 + (lane - 32));
    #pragma unroll 16
    for (int k = 0; k < HH; k++) {
        float s = __shfl(nd, k, 64);
        uv = fmaf(s, We1[k * HH + lane], uv);
        vv = fmaf(s, We1[(HH + k) * HH + lane], vv);
        pq = fmaf(s, WdCol[k * 32], pq);
    }
    U[node * HH + lane] = uv;
    // V interleaved-4: elem (node>>2)*64 + h = L*64 + lane, comp node&3 (= wave)
    V4[(L * 64 + lane) * 4 + wave] = vv;
    if (lane < 32) {
        P[node * 32 + lane] = pq;
    } else {
        int k = lane - 32;
        Qt4[((k >> 2) * (BB * SS) + node) * 4 + (k & 3)] = pq;
    }

    sn_lds[wave][lane] = nd;
    __syncthreads();
    if (tid < 64)
        SN[L * 64 + tid] = (sn_lds[0][tid] + sn_lds[1][tid]) + (sn_lds[2][tid] + sn_lds[3][tid]);
}

__global__ __launch_bounds__(256, 4) void k_pairs(
    const float* __restrict__ wd2, const float* __restrict__ bd2,
    float* __restrict__ ws)
{
    const float*  U   = ws + OFF_U;
    const float4* V4  = (const float4*)(ws + OFF_V);
    const float*  P   = ws + OFF_P;
    const float4* Qt4 = (const float4*)(ws + OFF_QT);
    float* SA = ws + OFF_SA;  float* SHo = ws + OFF_SH;  float* SKp = ws + OFF_SKP;

    __shared__ float4 gs[4][64];               // per-wave gate rows (i0..i3 per j)
    __shared__ float redA[4][64], redH[4][64], redK[4];

    const int tid = threadIdx.x, wave = tid >> 6, lane = tid & 63;
    // XCD co-location decode: XCD (d&7) = (b, jc) pair whose 256-node V/Qt chunk
    // was written by k_nodes on the same XCD -> all V/Qt reads are local-L2 hits.
    const int d   = blockIdx.x;
    const int xcd = d & 7;
    const int b   = xcd >> 1;
    const int jc  = xcd & 1;
    const int ic  = d >> 3;                    // 0..127
    const int i0  = ic * IPB;
    const int lidx = (b << 8) | (ic << 1) | jc;        // logical partial index (as before)
    const int jbase = b * SS + jc * 256 + wave * 64;   // this wave's 64 j's (global)

    // ---- issue-early staging: Qt (gate inputs) + first half of V ----
    const float4* Qp = Qt4 + jbase + lane;
    const float4* Vp = V4 + (jbase >> 2) * 64 + lane;
    float4 q[8], v[16];
    #pragma unroll
    for (int kg = 0; kg < 8; kg++) q[kg] = Qp[kg * (BB * SS)];
    #pragma unroll
    for (int jq = 0; jq < 8; jq++) v[jq] = Vp[jq * 64];

    // ---- block inputs ----
    const float u0 = U[(b * SS + i0 + 0) * HH + lane];
    const float u1 = U[(b * SS + i0 + 1) * HH + lane];
    const float u2 = U[(b * SS + i0 + 2) * HH + lane];
    const float u3 = U[(b * SS + i0 + 3) * HH + lane];
    const float pk0 = P[(b * SS + i0 + 0) * 32 + (lane & 31)];
    const float pk1 = P[(b * SS + i0 + 1) * 32 + (lane & 31)];
    const float pk2 = P[(b * SS + i0 + 2) * 32 + (lane & 31)];
    const float pk3 = P[(b * SS + i0 + 3) * 32 + (lane & 31)];
    const float wv  = wd2[lane & 31];
    const float bd2v = bd2[0];

    // ---- gate: lane <-> j; V loads still in flight underneath ----
    float a0 = bd2v, a1 = bd2v, a2 = bd2v, a3 = bd2v;
    #pragma unroll
    for (int kg = 0; kg < 8; kg++) {
        #pragma unroll
        for (int t = 0; t < 4; t++) {
            const int k = kg * 4 + t;
            float qv = (t == 0) ? q[kg].x : (t == 1) ? q[kg].y : (t == 2) ? q[kg].z : q[kg].w;
            float w  = rl(wv, k);
            a0 = fmaf(w, fmaxf(rl(pk0, k) + qv, 0.0f), a0);
            a1 = fmaf(w, fmaxf(rl(pk1, k) + qv, 0.0f), a1);
            a2 = fmaf(w, fmaxf(rl(pk2, k) + qv, 0.0f), a2);
            a3 = fmaf(w, fmaxf(rl(pk3, k) + qv, 0.0f), a3);
        }
    }
    float g0 = 1.0f / (1.0f + __expf(-a0));
    float g1 = 1.0f / (1.0f + __expf(-a1));
    float g2 = 1.0f / (1.0f + __expf(-a2));
    float g3 = 1.0f / (1.0f + __expf(-a3));
    float sk = (g0 + g1) + (g2 + g3);
    gs[wave][lane] = make_float4(g0, g1, g2, g3);

    // ---- issue second half of V; first half lands about now ----
    #pragma unroll
    for (int jq = 8; jq < 16; jq++) v[jq] = Vp[jq * 64];
    __builtin_amdgcn_wave_barrier();

    // ---- accumulate: lane <-> h comp, all data in registers ----
    float sa = 0.0f, sh = 0.0f;
    #pragma unroll
    for (int jq = 0; jq < 16; jq++) {
        #pragma unroll
        for (int t = 0; t < 4; t++) {
            float vv = (t == 0) ? v[jq].x : (t == 1) ? v[jq].y : (t == 2) ? v[jq].z : v[jq].w;
            float4 g4 = gs[wave][jq * 4 + t];              // uniform b128 broadcast
            float h0 = fmaxf(u0 + vv, 0.0f);
            float h1 = fmaxf(u1 + vv, 0.0f);
            float h2 = fmaxf(u2 + vv, 0.0f);
            float h3 = fmaxf(u3 + vv, 0.0f);
            sh += (h0 + h1) + (h2 + h3);
            sa = fmaf(g4.x, h0, sa);
            sa = fmaf(g4.y, h1, sa);
            sa = fmaf(g4.z, h2, sa);
            sa = fmaf(g4.w, h3, sa);
        }
    }

    redA[wave][lane] = sa;
    redH[wave][lane] = sh;
    #pragma unroll
    for (int off = 32; off; off >>= 1) sk += __shfl_xor(sk, off, 64);
    if (lane == 0) redK[wave] = sk;
    __syncthreads();

    // ---- plain coalesced partial stores at LOGICAL index ----
    if (tid < 64) {
        SA[lidx * 64 + tid]  = (redA[0][tid] + redA[1][tid]) + (redA[2][tid] + redA[3][tid]);
        SHo[lidx * 64 + tid] = (redH[0][tid] + redH[1][tid]) + (redH[2][tid] + redH[3][tid]);
        if (tid == 0)
            SKp[lidx * 16] = (redK[0] + redK[1]) + (redK[2] + redK[3]);
    }
}

__global__ __launch_bounds__(256) void k_final(
    const float* __restrict__ We2, const float* __restrict__ be2,
    const float* __restrict__ Wc1, const float* __restrict__ bc1,
    const float* __restrict__ Wc2, const float* __restrict__ bc2,
    const float* __restrict__ ws, float* __restrict__ out)
{
    const float4* SN4 = (const float4*)(ws + OFF_SN);   // [512 rows][16]
    const float4* SA4 = (const float4*)(ws + OFF_SA);   // [1024 rows][16]
    const float4* SH4 = (const float4*)(ws + OFF_SH);
    const float*  SKp = ws + OFF_SKP;
    __shared__ float4 r4[3][16][16];                    // [arr][grp][l16]
    __shared__ float redS[256], saL[64], shL[64];
    __shared__ float featL[128], c1L[32];
    const int tid = threadIdx.x, wave = tid >> 6, lane = tid & 63;
    const int grp = tid >> 4, l16 = tid & 15;
    const int b = blockIdx.x;                  // 4 blocks, one per batch

    // ---- float4 partial sums: fat loads ----
    float4 sn4 = make_float4(0.f, 0.f, 0.f, 0.f);
    float4 sa4 = sn4, sh4 = sn4;
    #pragma unroll
    for (int r = 0; r < 8; r++) {              // SN: 128 rows/batch
        float4 t = SN4[(b * 128 + r * 16 + grp) * 16 + l16];
        sn4.x += t.x; sn4.y += t.y; sn4.z += t.z; sn4.w += t.w;
    }
    #pragma unroll
    for (int r = 0; r < 16; r++) {             // SA/SH: 256 rows/batch
        float4 t = SA4[(b * 256 + r * 16 + grp) * 16 + l16];
        float4 u = SH4[(b * 256 + r * 16 + grp) * 16 + l16];
        sa4.x += t.x; sa4.y += t.y; sa4.z += t.z; sa4.w += t.w;
        sh4.x += u.x; sh4.y += u.y; sh4.z += u.z; sh4.w += u.w;
    }
    r4[0][grp][l16] = sn4;  r4[1][grp][l16] = sa4;  r4[2][grp][l16] = sh4;
    redS[tid] = SKp[(b * 256 + tid) * 16];
    __syncthreads();

    if (wave == 0) {                           // lane = tid, one h each
        const int li = lane >> 2, comp = lane & 3;
        float snT = 0.f, saF = 0.f, shF = 0.f;
        #pragma unroll
        for (int g = 0; g < 16; g++) {
            snT += ((const float*)&r4[0][g][li])[comp];
            saF += ((const float*)&r4[1][g][li])[comp];
            shF += ((const float*)&r4[2][g][li])[comp];
        }
        float skp = (redS[lane] + redS[64 + lane]) + (redS[128 + lane] + redS[192 + lane]);
        #pragma unroll
        for (int off = 32; off; off >>= 1) skp += __shfl_xor(skp, off, 64);
        saL[lane] = saF;  shL[lane] = shF;

        float as = skp * be2[lane];
        float ts = (262144.0f - skp) * be2[lane];     // S*S - SK
        #pragma unroll 8
        for (int k = 0; k < HH; k++) {
            float w = We2[k * HH + lane];
            float sak = saL[k];
            as = fmaf(sak, w, as);
            ts = fmaf(shL[k] - sak, w, ts);
        }
        featL[lane]      = (snT + as) * (1.0f / 512.0f);
        featL[64 + lane] = ts * (1.0f / 512.0f);
    }
    __syncthreads();

    if (tid < 32) {
        float c1 = bc1[tid];
        #pragma unroll 8
        for (int k = 0; k < 128; k++)
            c1 = fmaf(featL[k], Wc1[k * 32 + tid], c1);
        c1L[tid] = fmaxf(c1, 0.0f);
    }
    __syncthreads();
    if (tid < NCC) {
        float o = bc2[tid];
        #pragma unroll
        for (int k = 0; k < 32; k++)
            o = fmaf(c1L[k], Wc2[k * NCC + tid], o);
        out[b * NCC + tid] = o;
    }
}

extern "C" void kernel_launch(void* const* d_in, const int* in_sizes, int n_in,
                              void* d_out, int out_size, void* d_ws, size_t ws_size,
                              hipStream_t stream) {
    const float* x   = (const float*)d_in[0];
    const float* W1  = (const float*)d_in[1];
    const float* b1  = (const float*)d_in[2];
    const float* W2  = (const float*)d_in[3];
    const float* b2  = (const float*)d_in[4];
    const float* We1 = (const float*)d_in[5];
    const float* be1 = (const float*)d_in[6];
    const float* We2 = (const float*)d_in[7];
    const float* be2 = (const float*)d_in[8];
    const float* Wd1 = (const float*)d_in[9];
    const float* bd1 = (const float*)d_in[10];
    const float* wd2 = (const float*)d_in[11];
    const float* bd2 = (const float*)d_in[12];
    const float* Wc1 = (const float*)d_in[13];
    const float* bc1 = (const float*)d_in[14];
    const float* Wc2 = (const float*)d_in[15];
    const float* bc2 = (const float*)d_in[16];
    float* ws  = (float*)d_ws;
    float* out = (float*)d_out;

    k_nodes<<<dim3(NNB), dim3(256), 0, stream>>>(x, W1, b1, W2, b2, We1, be1, Wd1, bd1, ws);
    k_pairs<<<dim3(NPB), dim3(256), 0, stream>>>(wd2, bd2, ws);
    k_final<<<dim3(BB), dim3(256), 0, stream>>>(We2, be2, Wc1, bc1, Wc2, bc2, ws, out);
}